// Round 12
// baseline (870.404 us; speedup 1.0000x reference)
//
#include <hip/hip_runtime.h>
#include <math.h>

#define CC 192
#define TTT 768
#define PP 29
#define LOG2PI_F 1.8378770664093453f
#define WSLOT 36864   // swizzled 192x192 slot (elements)
#define PSW 6144      // swizzled 32x192 proj slot (elements)
#define XS 200        // ushort stride for trans_conv LDS tile
#define XSP 200       // ushort stride for mega ping rows
#define PARL 1728     // 9*192 floats per layer param block
#define NTH 320       // mega block: 5 waves
#define WIN 80        // mega window rows (48 out + 16 halo each side)
#define OUT 48        // mega output columns per block

typedef __attribute__((ext_vector_type(8))) short short8;
typedef __attribute__((ext_vector_type(4))) float floatx4;
typedef __attribute__((ext_vector_type(2))) float float2v;
union Frag { int4 i; short8 s; };

__device__ __forceinline__ float2v fma2(float2v a, float2v b, float2v c){
  return __builtin_elementwise_fma(a, b, c);
}
__device__ __forceinline__ float geluf(float x){
  float u = 1.5957691216057308f * (x + 0.044715f*x*x*x);
  return x * __builtin_amdgcn_rcpf(1.f + __expf(-u));
}
__device__ __forceinline__ float softplus_f(float x){
  return (x > 20.f) ? x : log1pf(__expf(x));
}
__device__ __forceinline__ float logsig_f(float x){
  return -softplus_f(-x);
}
__device__ __forceinline__ unsigned short f2bf(float f){
  unsigned int u = __builtin_bit_cast(unsigned int, f);
  u += 0x7fffu + ((u >> 16) & 1u);
  return (unsigned short)(u >> 16);
}
// HW packed f32->bf16 (RNE, matches f2bf). REGIME NOTE (r7-r10 2x2): profiles
// slower serialized/cold (latency-bound) but wins on the warm graded wall
// (680/680/676 vs 742/754). Trust wall A/Bs for VALU-side changes.
__device__ __forceinline__ unsigned int packbf2(float a0, float a1){
  unsigned int r;
  asm("v_cvt_pk_bf16_f32 %0, %1, %2" : "=v"(r) : "v"(a0), "v"(a1));
  return r;
}
__device__ __forceinline__ void unbf2(unsigned int u, float& lo, float& hi){
  lo = __builtin_bit_cast(float, u << 16);
  hi = __builtin_bit_cast(float, u & 0xffff0000u);
}
__device__ __forceinline__ float2v unbf2v(unsigned int u){
  float2v r;
  r.x = __builtin_bit_cast(float, u << 16);
  r.y = __builtin_bit_cast(float, u & 0xffff0000u);
  return r;
}
__device__ __forceinline__ void unp8(int4 v, float* o){
  unsigned int* p = (unsigned int*)&v;
  unbf2(p[0], o[0], o[1]); unbf2(p[1], o[2], o[3]);
  unbf2(p[2], o[4], o[5]); unbf2(p[3], o[6], o[7]);
}
__device__ __forceinline__ void f4arr(float4 v, float* o){ o[0]=v.x;o[1]=v.y;o[2]=v.z;o[3]=v.w; }
__device__ __forceinline__ float2v pick2(float4 a, float4 b, int p){
  switch(p){
    case 0: return (float2v){a.x, a.y};
    case 1: return (float2v){a.z, a.w};
    case 2: return (float2v){b.x, b.y};
    default: return (float2v){b.z, b.w};
  }
}

// ---------------- weight f32 -> bf16 swizzled fragment order ----------------
__global__ __launch_bounds__(256) void convert_w_k(
    const float* __restrict__ p0, const float* __restrict__ p1,
    const float* __restrict__ p2, const float* __restrict__ p3,
    const float* __restrict__ p4, const float* __restrict__ p5,
    const float* __restrict__ p6, const float* __restrict__ p7,
    const float* __restrict__ p8, unsigned short* __restrict__ Wb){
  int i = blockIdx.x*256 + threadIdx.x;
  const int totalA = 33*WSLOT;
  const int total = totalA + 8*PSW;
  if (i >= total) return;
  if (i < totalA){
    int slot = i / WSLOT, j = i % WSLOT;
    int e = j & 7, lane = (j>>3) & 63, kt = j >> 9;
    int k = kt % 6, tile = kt / 6;
    int co = tile*16 + (lane & 15);
    int kk = k*32 + (lane>>4)*8 + e;
    int r = co*CC + kk;
    const float* src;
    if      (slot == 0) src = p0 + r;
    else if (slot == 1) src = p1 + r;
    else if (slot == 2) src = p2 + r;
    else if (slot < 6)  src = p3 + (size_t)(slot-3)*WSLOT + r;
    else if (slot < 9)  src = p4 + (size_t)(slot-6)*WSLOT + r;
    else if (slot < 21) src = p5 + (size_t)(slot-9)*WSLOT + r;
    else                src = p6 + (size_t)(slot-21)*WSLOT + r;
    Wb[i] = f2bf(*src);
  } else {
    int r2 = i - totalA;
    int ps = r2 / PSW, j = r2 % PSW;
    int e = j & 7, lane = (j>>3) & 63, kt = j >> 9;
    int k = kt % 6, tile = kt / 6;
    int co = tile*16 + (lane & 15); if (co > PP-1) co = PP-1;
    int kk = k*32 + (lane>>4)*8 + e;
    const float* base = (ps < 4) ? (p7 + (size_t)ps*PP*CC) : (p8 + (size_t)(ps-4)*PP*CC);
    Wb[i] = f2bf(base[co*CC + kk]);
  }
}

// ---------------- per-layer params -> [set][layer][9][192] f32 ----------------
__global__ __launch_bounds__(256) void pack_par_k(
    const float* __restrict__ dds_dep_w, const float* __restrict__ dds_dep_b,
    const float* __restrict__ dds_ln_g,  const float* __restrict__ dds_ln_b,
    const float* __restrict__ dds_pw_b,
    const float* __restrict__ pdds_dep_w, const float* __restrict__ pdds_dep_b,
    const float* __restrict__ pdds_ln_g,  const float* __restrict__ pdds_ln_b,
    const float* __restrict__ pdds_pw_b,
    const float* __restrict__ p_dep_w, const float* __restrict__ p_dep_b,
    const float* __restrict__ p_ln_g,  const float* __restrict__ p_ln_b,
    const float* __restrict__ p_pw_b,
    const float* __restrict__ f_dep_w, const float* __restrict__ f_dep_b,
    const float* __restrict__ f_ln_g,  const float* __restrict__ f_ln_b,
    const float* __restrict__ f_pw_b,
    float* __restrict__ P){
  int i = blockIdx.x*256 + threadIdx.x;
  const int total = 30*PARL;
  if (i >= total) return;
  int ls = i / PARL, r = i % PARL;
  int arr = r / 192, c = r % 192;
  const float *dep_w, *dep_b, *ln_g, *ln_b, *pw_b;
  int l;
  if (ls < 3){
    l = ls; dep_w = dds_dep_w; dep_b = dds_dep_b; ln_g = dds_ln_g; ln_b = dds_ln_b; pw_b = dds_pw_b;
  } else if (ls < 6){
    l = ls-3; dep_w = pdds_dep_w; dep_b = pdds_dep_b; ln_g = pdds_ln_g; ln_b = pdds_ln_b; pw_b = pdds_pw_b;
  } else if (ls < 18){
    int f = (ls-6)/3; l = (ls-6)%3;
    dep_w = p_dep_w + (size_t)f*3*CC*3; dep_b = p_dep_b + (size_t)f*3*CC;
    ln_g = p_ln_g + (size_t)f*3*2*CC;  ln_b = p_ln_b + (size_t)f*3*2*CC;
    pw_b = p_pw_b + (size_t)f*3*CC;
  } else {
    int f = (ls-18)/3; l = (ls-18)%3;
    dep_w = f_dep_w + (size_t)f*3*CC*3; dep_b = f_dep_b + (size_t)f*3*CC;
    ln_g = f_ln_g + (size_t)f*3*2*CC;  ln_b = f_ln_b + (size_t)f*3*2*CC;
    pw_b = f_pw_b + (size_t)f*3*CC;
  }
  float v;
  if      (arr < 3)  v = dep_w[((size_t)l*CC + c)*3 + arr];
  else if (arr == 3) v = dep_b[(size_t)l*CC + c];
  else if (arr == 4) v = ln_g[((size_t)l*2+0)*CC + c];
  else if (arr == 5) v = ln_b[((size_t)l*2+0)*CC + c];
  else if (arr == 6) v = ln_g[((size_t)l*2+1)*CC + c];
  else if (arr == 7) v = ln_b[((size_t)l*2+1)*CC + c];
  else               v = pw_b[(size_t)l*CC + c];
  P[i] = v;
}

// -------- fused: x f32 [B][C][T] -> transpose -> conv1x1(pre) -> A bf16 [B][T][C] ----
__global__ __launch_bounds__(256) void trans_conv_k(
    const float* __restrict__ x, const unsigned short* __restrict__ Wsw,
    const float* __restrict__ bias, unsigned short* __restrict__ outb){
  __shared__ unsigned short bufX[32*XS];
  int b = blockIdx.y, t0 = blockIdx.x*32, tid = threadIdx.x;
  int tl4 = (tid & 7)*4, cr = tid >> 3;
  #pragma unroll
  for (int rnd=0; rnd<6; rnd++){
    int c = rnd*32 + cr;
    float4 v4 = *(const float4*)(x + ((size_t)b*CC + c)*TTT + t0 + tl4);
    bufX[(tl4+0)*XS + c] = f2bf(v4.x);
    bufX[(tl4+1)*XS + c] = f2bf(v4.y);
    bufX[(tl4+2)*XS + c] = f2bf(v4.z);
    bufX[(tl4+3)*XS + c] = f2bf(v4.w);
  }
  __syncthreads();
  int w = tid >> 6, lane = tid & 63;
  int n16 = lane & 15, quad = lane >> 4;
  Frag af[3][6];
  #pragma unroll
  for (int ct=0; ct<3; ct++){
    int tile = w*3 + ct;
    #pragma unroll
    for (int k=0;k<6;k++)
      af[ct][k].i = *(const int4*)(Wsw + ((size_t)(tile*6 + k)*64 + lane)*8);
  }
  floatx4 acc[3][2];
  #pragma unroll
  for (int ct=0;ct<3;ct++)
    #pragma unroll
    for (int tt=0;tt<2;tt++)
      acc[ct][tt] = (floatx4){0.f,0.f,0.f,0.f};
  #pragma unroll
  for (int k=0;k<6;k++){
    Frag bf[2];
    #pragma unroll
    for (int tt=0;tt<2;tt++)
      bf[tt].i = *(const int4*)&bufX[(tt*16+n16)*XS + k*32 + quad*8];
    #pragma unroll
    for (int ct=0;ct<3;ct++)
      #pragma unroll
      for (int tt=0;tt<2;tt++)
        acc[ct][tt] = __builtin_amdgcn_mfma_f32_16x16x32_bf16(af[ct][k].s, bf[tt].s, acc[ct][tt], 0,0,0);
  }
  __syncthreads();
  #pragma unroll
  for (int ct=0;ct<3;ct++){
    int cobase = w*48 + ct*16 + quad*4;
    float4 b4 = *(const float4*)(bias + cobase);
    #pragma unroll
    for (int tt=0;tt<2;tt++){
      int t = tt*16 + n16;
      uint2 wv;
      wv.x = packbf2(acc[ct][tt][0] + b4.x, acc[ct][tt][1] + b4.y);
      wv.y = packbf2(acc[ct][tt][2] + b4.z, acc[ct][tt][3] + b4.w);
      *(uint2*)&bufX[t*XS + cobase] = wv;
    }
  }
  __syncthreads();
  #pragma unroll
  for (int k=0;k<3;k++){
    int task = k*256 + tid;
    int row = task/24, cn = task%24;
    *(int4*)(outb + ((size_t)b*TTT + t0 + row)*CC + cn*8) = *(const int4*)&bufX[row*XS + cn*8];
  }
}

// ---------------- one fused DDS layer, compile-time peeled (48-col tile) --------
// 5 waves x 16 rows cover the 80-row window for layers 0,1 (all active, NT=12).
// SPLITF=1 (layer 2, dil 9): only center 48 rows matter; waves 0..2 own 16 rows
// each with ALL 12 co-tiles (full LN stats in-wave, no exchange); waves 3,4 idle.
// Rules (r1-r3): static register-array indices; no pre-barrier prefetch with
// cross-barrier register liveness. P4: depth-1 double-buffer.
template<int DIL, int SPLITF>
__device__ __forceinline__ void dds_layer(
    unsigned short* __restrict__ ping,
    const float* __restrict__ pl,
    float* __restrict__ pnd, const float* __restrict__ pns,
    const float* __restrict__ mrow,
    const unsigned short* __restrict__ WL,
    int tid, int w, int lane, int n16, int quad, int row){
  const bool active = (!SPLITF) || (w < 3);
  const int rowL = SPLITF ? (16 + (w < 3 ? w : 0)*16 + n16) : row;
  Frag bfr[6];
  floatx4 acc[12];
  if (active){
    int iL = rowL - DIL; iL = iL < 0 ? 0 : iL;
    int iR = rowL + DIL; iR = iR > WIN-1 ? WIN-1 : iR;
    float2v vv[24];
    float2v s2v = {0.f,0.f}, q2v = {0.f,0.f};
    #pragma unroll
    for (int j=0;j<6;j++){
      int kk = j*32 + quad*8;
      int4 L4 = *(const int4*)&ping[iL*XSP + kk];
      int4 C4 = *(const int4*)&ping[rowL*XSP + kk];
      int4 R4 = *(const int4*)&ping[iR*XSP + kk];
      unsigned int* Lp = (unsigned int*)&L4;
      unsigned int* Cp = (unsigned int*)&C4;
      unsigned int* Rp = (unsigned int*)&R4;
      float4 w0a = *(const float4*)&pl[kk],       w0b = *(const float4*)&pl[kk+4];
      float4 w1a = *(const float4*)&pl[192+kk],   w1b = *(const float4*)&pl[192+kk+4];
      float4 w2a = *(const float4*)&pl[384+kk],   w2b = *(const float4*)&pl[384+kk+4];
      float4 dba = *(const float4*)&pl[576+kk],   dbb = *(const float4*)&pl[576+kk+4];
      #pragma unroll
      for (int p=0;p<4;p++){
        float2v val = fma2(pick2(w0a,w0b,p), unbf2v(Lp[p]),
                      fma2(pick2(w1a,w1b,p), unbf2v(Cp[p]),
                      fma2(pick2(w2a,w2b,p), unbf2v(Rp[p]), pick2(dba,dbb,p))));
        vv[j*4+p] = val;
        s2v += val;
        q2v = fma2(val, val, q2v);
      }
    }
    float s = s2v.x + s2v.y, q = q2v.x + q2v.y;
    s += __shfl_xor(s, 16); s += __shfl_xor(s, 32);
    q += __shfl_xor(q, 16); q += __shfl_xor(q, 32);
    float mm = s*(1.f/CC);
    float rr = rsqrtf(q*(1.f/CC) - mm*mm + 1e-5f);
    // P3: LN + gelu -> B fragments in registers
    float2v mm2 = {mm,mm}, rr2 = {rr,rr};
    #pragma unroll
    for (int j=0;j<6;j++){
      int kk = j*32 + quad*8;
      float4 g0a = *(const float4*)&pl[768+kk], g0b = *(const float4*)&pl[768+kk+4];
      float4 b0a = *(const float4*)&pl[960+kk], b0b = *(const float4*)&pl[960+kk+4];
      unsigned int wwp[4];
      #pragma unroll
      for (int p=0;p<4;p++){
        float2v a = fma2((vv[j*4+p]-mm2)*rr2, pick2(g0a,g0b,p), pick2(b0a,b0b,p));
        wwp[p] = packbf2(geluf(a.x), geluf(a.y));
      }
      bfr[j].i = make_int4((int)wwp[0], (int)wwp[1], (int)wwp[2], (int)wwp[3]);
    }
  }
  __syncthreads();   // all P1 ping reads done before in-place P6 writes
  // stage next layer's params (overlaps P4; visible at end-of-layer barrier)
  if (pns){
    #pragma unroll
    for (int k=0;k<6;k++){
      int i2 = k*NTH + tid;
      if (i2 < PARL) pnd[i2] = pns[i2];
    }
  }
  if (active){
    // P4: stream 12 A-tiles with depth-1 software double-buffer, B from registers
    {
      Frag afb[2][6];
      #pragma unroll
      for (int k=0;k<6;k++)
        afb[0][k].i = *(const int4*)(WL + ((size_t)(0*6 + k)*64 + lane)*8);
      #pragma unroll
      for (int tile=0; tile<12; tile++){
        int cur = tile & 1, nxt = cur ^ 1;
        if (tile < 11){
          #pragma unroll
          for (int k=0;k<6;k++)
            afb[nxt][k].i = *(const int4*)(WL + ((size_t)((tile+1)*6 + k)*64 + lane)*8);
        }
        acc[tile] = (floatx4){0.f,0.f,0.f,0.f};
        #pragma unroll
        for (int k=0;k<6;k++)
          acc[tile] = __builtin_amdgcn_mfma_f32_16x16x32_bf16(afb[cur][k].s, bfr[k].s, acc[tile], 0,0,0);
      }
    }
    // bias + conv-LN stats (packed, in-wave; full 192 couts per wave)
    float2v s2p = {0.f,0.f}, q2p = {0.f,0.f};
    #pragma unroll
    for (int tile=0; tile<12; tile++){
      int co = tile*16 + quad*4;
      float4 pbv = *(const float4*)&pl[1536+co];
      acc[tile][0] += pbv.x; acc[tile][1] += pbv.y;
      acc[tile][2] += pbv.z; acc[tile][3] += pbv.w;
      float2v v01 = {acc[tile][0], acc[tile][1]};
      float2v v23 = {acc[tile][2], acc[tile][3]};
      s2p += v01 + v23;
      q2p = fma2(v01, v01, q2p);
      q2p = fma2(v23, v23, q2p);
    }
    float s2 = s2p.x + s2p.y, q2 = q2p.x + q2p.y;
    s2 += __shfl_xor(s2, 16); s2 += __shfl_xor(s2, 32);
    q2 += __shfl_xor(q2, 16); q2 += __shfl_xor(q2, 32);
    float cmP = s2*(1.f/CC);
    float crP = rsqrtf(q2*(1.f/CC) - cmP*cmP + 1e-5f);
    // P6: LN + gelu + residual, apply row mask, in-place
    float mc = mrow[rowL];
    float2v mc2 = {mc,mc};
    float2v cm2 = {cmP,cmP}, cr2 = {crP,crP};
    #pragma unroll
    for (int tile=0; tile<12; tile++){
      int co = tile*16 + quad*4;
      float4 g1v = *(const float4*)&pl[1152+co];
      float4 b1v = *(const float4*)&pl[1344+co];
      uint2 ux = *(uint2*)&ping[rowL*XSP + co];
      float2v x01 = unbf2v(ux.x), x23 = unbf2v(ux.y);
      float2v v01 = {acc[tile][0], acc[tile][1]};
      float2v v23 = {acc[tile][2], acc[tile][3]};
      float2v a01 = fma2((v01-cm2)*cr2, (float2v){g1v.x,g1v.y}, (float2v){b1v.x,b1v.y});
      float2v a23 = fma2((v23-cm2)*cr2, (float2v){g1v.z,g1v.w}, (float2v){b1v.z,b1v.w});
      float2v h01 = (x01 + (float2v){geluf(a01.x), geluf(a01.y)}) * mc2;
      float2v h23 = (x23 + (float2v){geluf(a23.x), geluf(a23.y)}) * mc2;
      uint2 wv;
      wv.x = packbf2(h01.x, h01.y);
      wv.y = packbf2(h23.x, h23.y);
      *(uint2*)&ping[rowL*XSP + co] = wv;
    }
  }
  __syncthreads();   // P6 writes + par staging visible
}

// ---------------- mega DDS v15: 48-col tile, 5-wave block ----------------
// outmode=1: flow path (proj 29x192 + RQS). outmode=2: conv tail.
// pmode: 0 none; 1 init fused (p0); 2 transition-stage (f0); 3 transition-rqs (f1).
// finmode=1 (f3): adds 0.5(log2pi+z^2) of both final channels in RQS.
// Race audit unchanged: cross-block z traffic = halo READS of staged channel +
// benign pass-through writes old*m (binary mask).
__global__ __launch_bounds__(NTH,3) void mega_dds_k(
    const unsigned short* __restrict__ in,
    const float* __restrict__ zsrc, int zstride,
    const unsigned short* __restrict__ g,
    const float* __restrict__ mask,
    const float* __restrict__ parP,     // 3 layers x PARL floats
    const float* __restrict__ pw1, const float* __restrict__ pb1,
    const unsigned short* __restrict__ Wsw,
    int srcmode, int outmode,
    const unsigned short* __restrict__ projW, const float* __restrict__ projB,
    float* __restrict__ z, int zs, float* __restrict__ acco,
    const unsigned short* __restrict__ cvW, const float* __restrict__ cvB,
    const unsigned short* __restrict__ addsrc, unsigned short* __restrict__ cvout,
    int cvmode,
    int pmode, int finmode, const float* __restrict__ aux,
    const float* __restrict__ pmv, const float* __restrict__ plv){
  __shared__ unsigned short ping[WIN*XSP];  // bf16 [window row][c], masked residual stream
  __shared__ float par[2][PARL];            // per-layer params, double-buffered
  __shared__ float mrow[WIN];
  float* pro = par[0];                      // alias: 48*30=1440 <= PARL; used after layers

  int b = blockIdx.y, t0 = blockIdx.x*OUT, tid = threadIdx.x;
  int ws0 = t0 - 16;
  int w = tid >> 6, lane = tid & 63;
  int n16 = lane & 15, quad = lane >> 4;
  int row = w*16 + n16;                      // this lane's window row (layers 0,1)
  const float* mkb = mask + (size_t)b*TTT;

  // uniform per-mode scalars (affine constants)
  float pm0=0.f, pm1=0.f, lg0=0.f, lg1=0.f, ex0=0.f, ex1=0.f;
  if (pmode){
    pm0 = pmv[0]; pm1 = pmv[1]; lg0 = plv[0]; lg1 = plv[1];
    ex0 = __expf(lg0); ex1 = __expf(lg1);
  }

  if (tid < WIN){
    int gt = ws0 + tid;
    bool inr = (gt >= 0) && (gt < TTT);
    int gc = gt < 0 ? 0 : (gt > TTT-1 ? TTT-1 : gt);
    mrow[tid] = inr ? mkb[gc] : 0.f;
  }
  // stage layer-0 params
  #pragma unroll
  for (int k=0;k<6;k++){
    int i2 = k*NTH + tid;
    if (i2 < PARL) par[0][i2] = parP[i2];
  }
  // ---- staging (pre-masked): WIN*24 = 1920 tasks = 6*NTH exactly ----
  if (srcmode == 0){
    #pragma unroll
    for (int k=0;k<6;k++){
      int task = k*NTH + tid;
      int r = task/24, cn = task%24, c0 = cn*8;
      int gt = ws0 + r;
      bool inr = (gt >= 0) && (gt < TTT);
      int gc = gt < 0 ? 0 : (gt > TTT-1 ? TTT-1 : gt);
      float mv = inr ? mkb[gc] : 0.f;
      float hv[8];
      unp8(*(const int4*)(in + ((size_t)b*TTT + gc)*CC + c0), hv);
      int4 pk;
      pk.x = (int)packbf2(hv[0]*mv, hv[1]*mv); pk.y = (int)packbf2(hv[2]*mv, hv[3]*mv);
      pk.z = (int)packbf2(hv[4]*mv, hv[5]*mv); pk.w = (int)packbf2(hv[6]*mv, hv[7]*mv);
      *(int4*)&ping[r*XSP + c0] = pk;
    }
  } else {
    #pragma unroll
    for (int k=0;k<6;k++){
      int task = k*NTH + tid;
      int r = task/24, cn = task%24, c0 = cn*8;
      int gt = ws0 + r;
      bool inr = (gt >= 0) && (gt < TTT);
      int gc = gt < 0 ? 0 : (gt > TTT-1 ? TTT-1 : gt);
      float mv = inr ? mkb[gc] : 0.f;
      float zv;
      if (pmode == 1){
        float e0 = aux[((size_t)b*2+0)*TTT + gc] * mv;
        zv = fmaf(ex0, e0, pm0)*mv;
      } else if (pmode == 2){
        float zu = zsrc[(size_t)b*zstride + gc];
        float wv = aux[(size_t)b*TTT + gc];
        float u  = mv / (1.f + __expf(-zu));
        float y0 = logf(fmaxf((wv - u)*mv, 1e-5f))*mv;
        zv = fmaf(ex0, y0, pm0)*mv;
      } else {
        zv = inr ? zsrc[(size_t)b*zstride + gc] : 0.f;
      }
      float hv[8];
      if (g){
        unp8(*(const int4*)(g + ((size_t)b*TTT + gc)*CC + c0), hv);
      } else {
        #pragma unroll
        for (int e=0;e<8;e++) hv[e] = 0.f;
      }
      float4 pwa = *(const float4*)(pw1 + c0);
      float4 pwb2 = *(const float4*)(pw1 + c0 + 4);
      float4 pba = *(const float4*)(pb1 + c0);
      float4 pbb2 = *(const float4*)(pb1 + c0 + 4);
      float pwv[8], pbv[8];
      f4arr(pwa, pwv); f4arr(pwb2, pwv+4);
      f4arr(pba, pbv); f4arr(pbb2, pbv+4);
      float ov[8];
      #pragma unroll
      for (int e=0;e<8;e++) ov[e] = (hv[e] + fmaf(pwv[e], zv, pbv[e]))*mv;
      int4 pk;
      pk.x = (int)packbf2(ov[0], ov[1]); pk.y = (int)packbf2(ov[2], ov[3]);
      pk.z = (int)packbf2(ov[4], ov[5]); pk.w = (int)packbf2(ov[6], ov[7]);
      *(int4*)&ping[r*XSP + c0] = pk;
    }
  }
  __syncthreads();

  // ---- 3 fused layers, peeled with compile-time shapes ----
  dds_layer<1,0>(ping, par[0], par[1], parP + (size_t)1*PARL, mrow,
                 Wsw + 0*(size_t)WSLOT, tid, w, lane, n16, quad, row);
  dds_layer<3,0>(ping, par[1], par[0], parP + (size_t)2*PARL, mrow,
                 Wsw + 1*(size_t)WSLOT, tid, w, lane, n16, quad, row);
  dds_layer<9,1>(ping, par[0], nullptr, nullptr, mrow,
                 Wsw + 2*(size_t)WSLOT, tid, w, lane, n16, quad, row);

  if (outmode == 2){
    // ---- fused 192x192 conv tail on center rows 16..63 ----
    // waves 0..3: 3 co-tiles x 3 row-groups; wave 4 idle. addsrc read direct
    // from global in epilogue (warm L2) -- no halo staging.
    if (w < 4){
      Frag af[3][6];
      #pragma unroll
      for (int ct=0; ct<3; ct++){
        int tile = w*3 + ct;
        #pragma unroll
        for (int k=0;k<6;k++)
          af[ct][k].i = *(const int4*)(cvW + ((size_t)(tile*6 + k)*64 + lane)*8);
      }
      floatx4 acc2[3][3];
      #pragma unroll
      for (int ct=0;ct<3;ct++)
        #pragma unroll
        for (int tt=0;tt<3;tt++)
          acc2[ct][tt] = (floatx4){0.f,0.f,0.f,0.f};
      #pragma unroll
      for (int k=0;k<6;k++){
        Frag bf[3];
        #pragma unroll
        for (int tt=0;tt<3;tt++)
          bf[tt].i = *(const int4*)&ping[(16 + tt*16 + n16)*XSP + k*32 + quad*8];
        #pragma unroll
        for (int ct=0;ct<3;ct++)
          #pragma unroll
          for (int tt=0;tt<3;tt++)
            acc2[ct][tt] = __builtin_amdgcn_mfma_f32_16x16x32_bf16(af[ct][k].s, bf[tt].s, acc2[ct][tt], 0,0,0);
      }
      __syncthreads();   // center reads complete before in-place writes
      #pragma unroll
      for (int ct=0;ct<3;ct++){
        int cobase = w*48 + ct*16 + quad*4;
        float4 b4 = *(const float4*)(cvB + cobase);
        float ba[4] = {b4.x, b4.y, b4.z, b4.w};
        #pragma unroll
        for (int tt=0;tt<3;tt++){
          int t = tt*16 + n16;
          float mv = mrow[16 + t];
          float av[4] = {0.f,0.f,0.f,0.f};
          if (cvmode == 2){
            uint2 uy = *(const uint2*)(addsrc + ((size_t)b*TTT + t0 + t)*CC + cobase);
            unbf2(uy.x, av[0], av[1]); unbf2(uy.y, av[2], av[3]);
          }
          float hh[4];
          #pragma unroll
          for (int r=0;r<4;r++){
            float v = (acc2[ct][tt][r] + ba[r]) * mv;
            if (cvmode == 2) v += av[r];
            hh[r] = v;
          }
          uint2 wv; wv.x = packbf2(hh[0], hh[1]); wv.y = packbf2(hh[2], hh[3]);
          *(uint2*)&ping[(16 + t)*XSP + cobase] = wv;
        }
      }
    } else {
      __syncthreads();   // wave 4 matches the active waves' barrier
    }
    __syncthreads();
    #pragma unroll
    for (int k=0;k<4;k++){
      int task = k*NTH + tid;
      if (task < OUT*24){
        int r = task/24, cn = task%24, c0 = cn*8;
        *(int4*)(cvout + ((size_t)b*TTT + t0 + r)*CC + c0) = *(const int4*)&ping[(16+r)*XSP + c0];
      }
    }
    return;
  }

  // ---- proj (29x192) on center rows: waves 0..2 own 16 rows, 2 ct each ----
  if (w < 3){
    int prow = 16 + w*16 + n16;             // 16..63
    Frag bfp[6];
    #pragma unroll
    for (int k=0;k<6;k++)
      bfp[k].i = *(const int4*)&ping[prow*XSP + k*32 + quad*8];
    int rt = prow - 16;                     // 0..47
    float mv = mrow[prow];
    #pragma unroll
    for (int ctp=0; ctp<2; ctp++){
      floatx4 acc2 = (floatx4){0.f,0.f,0.f,0.f};
      #pragma unroll
      for (int k=0;k<6;k++){
        Frag afp;
        afp.i = *(const int4*)(projW + ((size_t)(ctp*6 + k)*64 + lane)*8);
        acc2 = __builtin_amdgcn_mfma_f32_16x16x32_bf16(afp.s, bfp[k].s, acc2, 0,0,0);
      }
      #pragma unroll
      for (int r=0;r<4;r++){
        int co = ctp*16 + quad*4 + r;
        if (co < PP) pro[rt*30 + co] = (acc2[r] + projB[co]) * mv;
      }
    }
  }
  __syncthreads();
  // ---- RQS spline: lanes 0..47 of wave 0 (+ fused init/transition/final) ----
  if (tid < 64){
    float c = 0.f;
    if (tid < OUT){
      const float scv = 0.07216878364870323f;   // 1/sqrt(192)
      int t = tid;
      int tg = t0 + t;
      float m = mrow[16+t];
      float* z0p = z + ((size_t)b*2 + zs)*TTT + tg;
      float* z1p = z + ((size_t)b*2 + (1-zs))*TTT + tg;
      float xs, zwr0, extra = 0.f;
      if (pmode == 1){
        float e0c = aux[((size_t)b*2+0)*TTT + tg]*m;
        float e1c = aux[((size_t)b*2+1)*TTT + tg]*m;
        zwr0 = fmaf(ex0, e0c, pm0)*m;
        xs   = fmaf(ex1, e1c, pm1)*m;
        extra = -0.5f*(LOG2PI_F + e0c*e0c)*m - 0.5f*(LOG2PI_F + e1c*e1c)*m - (lg0+lg1)*m;
      } else if (pmode == 2){
        xs = fmaf(ex1, *z1p, pm1)*m;
        zwr0 = (*z0p)*m;
      } else if (pmode == 3){
        float zu = *z1p;                    // ch pre-transition (center-local)
        float wv = aux[(size_t)b*TTT + tg];
        float u  = m/(1.f + __expf(-zu));
        float y0 = logf(fmaxf((wv - u)*m, 1e-5f))*m;
        xs = fmaf(ex0, y0, pm0)*m;
        extra = -(logsig_f(zu)+logsig_f(-zu))*m + y0 - (lg0+lg1)*m;
        zwr0 = (*z0p)*m;
      } else {
        xs = *z1p;
        zwr0 = (*z0p)*m;
      }
      float uw[10], uh[10], ud[9];
      #pragma unroll
      for (int k=0;k<10;k++) uw[k]=pro[t*30+k]*scv;
      #pragma unroll
      for (int k=0;k<10;k++) uh[k]=pro[t*30+10+k]*scv;
      #pragma unroll
      for (int k=0;k<9;k++)  ud[k]=pro[t*30+20+k];
      bool inside = (xs >= -5.f) && (xs <= 5.f);
      float xc = fminf(fmaxf(xs,-5.f),5.f);
      float mx=uw[0];
      #pragma unroll
      for (int k=1;k<10;k++) mx=fmaxf(mx,uw[k]);
      float sw=0.f; float wd[10];
      #pragma unroll
      for (int k=0;k<10;k++){ wd[k]=__expf(uw[k]-mx); sw+=wd[k]; }
      float invw = 1.f/sw;
      #pragma unroll
      for (int k=0;k<10;k++) wd[k]=fmaf(0.99f*invw, wd[k], 1e-3f);
      float mh=uh[0];
      #pragma unroll
      for (int k=1;k<10;k++) mh=fmaxf(mh,uh[k]);
      float sh=0.f; float ht[10];
      #pragma unroll
      for (int k=0;k<10;k++){ ht[k]=__expf(uh[k]-mh); sh+=ht[k]; }
      float invh = 1.f/sh;
      #pragma unroll
      for (int k=0;k<10;k++) ht[k]=fmaf(0.99f*invh, ht[k], 1e-3f);
      float cw=-5.f, icw=-5.f, iw=1.f; int idx=0;
      #pragma unroll
      for (int i2=0;i2<10;i2++){
        float nw = (i2==9) ? 5.f : fmaf(10.f, wd[i2], cw);
        if (cw <= xc){ idx=i2; icw=cw; iw=nw-cw; }
        cw=nw;
      }
      float ch=-5.f, ich=-5.f, ih=1.f;
      #pragma unroll
      for (int i2=0;i2<10;i2++){
        float nh = (i2==9) ? 5.f : fmaf(10.f, ht[i2], ch);
        if (i2==idx){ ich=ch; ih=nh-ch; }
        ch=nh;
      }
      const float UDC = logf(expm1f(0.999f));
      float d0=1.f, d1=1.f;
      #pragma unroll
      for (int k=0;k<11;k++){
        float uu = (k==0 || k==10) ? UDC : ud[k-1];
        float dk = 1e-3f + softplus_f(uu);
        if (k==idx)   d0=dk;
        if (k==idx+1) d1=dk;
      }
      float idel = ih/iw;
      float th = (xc-icw)/iw;
      float t1m = th*(1.f-th);
      float den = idel + (d0+d1-2.f*idel)*t1m;
      float outv = ich + ih*(idel*th*th + d0*t1m)/den;
      float omt = 1.f-th;
      float dnum = idel*idel*(d1*th*th + 2.f*idel*t1m + d0*omt*omt);
      float lad = logf(dnum) - 2.f*logf(den);
      float y = inside ? outv : xs;
      lad = inside ? lad : 0.f;
      float y1 = y*m;
      *z1p = y1;
      *z0p = zwr0;
      if (finmode){
        extra += 0.5f*(LOG2PI_F + y1*y1)*m + 0.5f*(LOG2PI_F + zwr0*zwr0)*m;
      }
      c = extra - lad*m;
    }
    c += __shfl_xor(c, 1); c += __shfl_xor(c, 2);
    c += __shfl_xor(c, 4); c += __shfl_xor(c, 8);
    c += __shfl_xor(c, 16); c += __shfl_xor(c, 32);
    if (tid == 0) atomicAdd(acco + b, c);
  }
}

__global__ void write_out_k(const float* __restrict__ acc, float* __restrict__ out, int n){
  int i = threadIdx.x;
  if (i < n) out[i] = acc[i];
}

extern "C" void kernel_launch(void* const* d_in, const int* in_sizes, int n_in,
                              void* d_out, int out_size, void* d_ws, size_t ws_size,
                              hipStream_t stream){
  (void)n_in; (void)out_size; (void)ws_size;
  const float* x         = (const float*)d_in[0];
  const float* mask      = (const float*)d_in[1];
  const float* w_in      = (const float*)d_in[2];
  const float* e_q       = (const float*)d_in[3];
  const float* pre_w     = (const float*)d_in[4];
  const float* pre_b     = (const float*)d_in[5];
  const float* proj_w    = (const float*)d_in[6];
  const float* proj_b    = (const float*)d_in[7];
  const float* dds_dep_w = (const float*)d_in[8];
  const float* dds_dep_b = (const float*)d_in[9];
  const float* dds_pw_w  = (const float*)d_in[10];
  const float* dds_pw_b  = (const float*)d_in[11];
  const float* dds_ln_g  = (const float*)d_in[12];
  const float* dds_ln_b  = (const float*)d_in[13];
  const float* post_pre_w  = (const float*)d_in[14];
  const float* post_pre_b  = (const float*)d_in[15];
  const float* post_proj_w = (const float*)d_in[16];
  const float* post_proj_b = (const float*)d_in[17];
  const float* pdds_dep_w  = (const float*)d_in[18];
  const float* pdds_dep_b  = (const float*)d_in[19];
  const float* pdds_pw_w   = (const float*)d_in[20];
  const float* pdds_pw_b   = (const float*)d_in[21];
  const float* pdds_ln_g   = (const float*)d_in[22];
  const float* pdds_ln_b   = (const float*)d_in[23];
  const float* aff_m    = (const float*)d_in[24];
  const float* aff_logs = (const float*)d_in[25];
  const float* f_pre_w  = (const float*)d_in[26];
  const float* f_pre_b  = (const float*)d_in[27];
  const float* f_dep_w  = (const float*)d_in[28];
  const float* f_dep_b  = (const float*)d_in[29];
  const float* f_pw_w   = (const float*)d_in[30];
  const float* f_pw_b   = (const float*)d_in[31];
  const float* f_ln_g   = (const float*)d_in[32];
  const float* f_ln_b   = (const float*)d_in[33];
  const float* f_proj_w = (const float*)d_in[34];
  const float* f_proj_b = (const float*)d_in[35];
  const float* paff_m    = (const float*)d_in[36];
  const float* paff_logs = (const float*)d_in[37];
  const float* p_pre_w  = (const float*)d_in[38];
  const float* p_pre_b  = (const float*)d_in[39];
  const float* p_dep_w  = (const float*)d_in[40];
  const float* p_dep_b  = (const float*)d_in[41];
  const float* p_pw_w   = (const float*)d_in[42];
  const float* p_pw_b   = (const float*)d_in[43];
  const float* p_ln_g   = (const float*)d_in[44];
  const float* p_ln_b   = (const float*)d_in[45];
  const float* p_proj_w = (const float*)d_in[46];
  const float* p_proj_b = (const float*)d_in[47];

  int Bn = in_sizes[0] / (CC*TTT);
  size_t big2 = (size_t)Bn*CC*TTT;
  unsigned short* xT = (unsigned short*)d_ws;   // slot kept for layout stability (unused)
  unsigned short* A  = xT + big2;
  unsigned short* Bb = A  + big2;               // unused
  unsigned short* H  = Bb + big2;
  unsigned short* GP = H  + big2;
  unsigned short* Wb = GP + big2;
  size_t wtot = 33*(size_t)WSLOT + 8*(size_t)PSW;
  float* parP = (float*)(Wb + ((wtot + 7) & ~(size_t)7));
  float* zbuf = parP + 30*(size_t)PARL;
  float* acc  = zbuf + (size_t)Bn*2*TTT;

  hipMemsetAsync(acc, 0, Bn*sizeof(float), stream);
  convert_w_k<<<(int)((wtot + 255)/256), 256, 0, stream>>>(
      pre_w, proj_w, post_proj_w, dds_pw_w, pdds_pw_w, p_pw_w, f_pw_w,
      p_proj_w, f_proj_w, Wb);
  pack_par_k<<<(30*PARL + 255)/256, 256, 0, stream>>>(
      dds_dep_w, dds_dep_b, dds_ln_g, dds_ln_b, dds_pw_b,
      pdds_dep_w, pdds_dep_b, pdds_ln_g, pdds_ln_b, pdds_pw_b,
      p_dep_w, p_dep_b, p_ln_g, p_ln_b, p_pw_b,
      f_dep_w, f_dep_b, f_ln_g, f_ln_b, f_pw_b, parP);

  dim3 g32(TTT/32, Bn), g48(TTT/OUT, Bn);
  dim3 b256(256), b320(NTH);

  unsigned short* W_pre      = Wb + 0*(size_t)WSLOT;
  unsigned short* W_proj     = Wb + 1*(size_t)WSLOT;
  unsigned short* W_postproj = Wb + 2*(size_t)WSLOT;
  unsigned short* W_dds      = Wb + 3*(size_t)WSLOT;
  unsigned short* W_pdds     = Wb + 6*(size_t)WSLOT;
  unsigned short* W_ppw      = Wb + 9*(size_t)WSLOT;
  unsigned short* W_fpw      = Wb + 21*(size_t)WSLOT;
  unsigned short* W_pproj    = Wb + 33*(size_t)WSLOT;
  unsigned short* W_fproj    = W_pproj + 4*(size_t)PSW;

  // ---- h path: [transpose + conv1x1(pre)] -> mega(+proj tail) -> H ----
  trans_conv_k<<<g32, b256, 0, stream>>>(x, W_pre, pre_b, A);
  mega_dds_k<<<g48, b320, 0, stream>>>(A, nullptr, 0, nullptr, mask,
      parP + 0*(size_t)3*PARL, nullptr, nullptr,
      W_dds, 0, 2, nullptr, nullptr, nullptr, 0, acc,
      W_proj, proj_b, nullptr, H, 1,
      0, 0, nullptr, nullptr, nullptr);

  // ---- hw path: mega(+postproj+H tail) -> GP ----
  mega_dds_k<<<g48, b320, 0, stream>>>(nullptr, w_in, TTT, nullptr, mask,
      parP + 1*(size_t)3*PARL, post_pre_w, post_pre_b,
      W_pdds, 1, 2, nullptr, nullptr, nullptr, 0, acc,
      W_postproj, post_proj_b, H, GP, 2,
      0, 0, nullptr, nullptr, nullptr);

  // ---- 4 posterior flows (g = GP, sets 2..5); flow 0 fuses z-init ----
  for (int f=0; f<4; f++){
    int s = f & 1;
    mega_dds_k<<<g48, b320, 0, stream>>>(nullptr, zbuf + (size_t)s*TTT, 2*TTT, GP, mask,
        parP + (size_t)(2+f)*3*PARL,
        p_pre_w + (size_t)f*CC, p_pre_b + (size_t)f*CC,
        W_ppw + (size_t)f*3*WSLOT, 1, 1,
        W_pproj + (size_t)f*PSW, p_proj_b + (size_t)f*PP, zbuf, s, acc,
        nullptr, nullptr, nullptr, nullptr, 0,
        (f==0) ? 1 : 0, 0, e_q, paff_m, paff_logs);
  }

  // ---- 4 flows (g = H, sets 6..9); flow 0/1 fuse transition, flow 3 fuses final ----
  for (int f=0; f<4; f++){
    int s = f & 1;
    int pmode = (f==0) ? 2 : ((f==1) ? 3 : 0);
    mega_dds_k<<<g48, b320, 0, stream>>>(nullptr, zbuf + (size_t)s*TTT, 2*TTT, H, mask,
        parP + (size_t)(6+f)*3*PARL,
        f_pre_w + (size_t)f*CC, f_pre_b + (size_t)f*CC,
        W_fpw + (size_t)f*3*WSLOT, 1, 1,
        W_fproj + (size_t)f*PSW, f_proj_b + (size_t)f*PP, zbuf, s, acc,
        nullptr, nullptr, nullptr, nullptr, 0,
        pmode, (f==3) ? 1 : 0, w_in, aff_m, aff_logs);
  }

  write_out_k<<<1, 64, 0, stream>>>(acc, (float*)d_out, Bn);
}

// Round 13
// 676.264 us; speedup vs baseline: 1.2871x; 1.2871x over previous
//
#include <hip/hip_runtime.h>
#include <math.h>

#define CC 192
#define TTT 768
#define PP 29
#define LOG2PI_F 1.8378770664093453f
#define WSLOT 36864   // swizzled 192x192 slot (elements)
#define PSW 6144      // swizzled 32x192 proj slot (elements)
#define XS 200        // ushort stride for trans_conv LDS tile
#define XSP 200       // ushort stride for mega ping (400B rows: 16B-aligned, 2-way bank alias = free)
#define PARL 1728     // 9*192 floats per layer param block

typedef __attribute__((ext_vector_type(8))) short short8;
typedef __attribute__((ext_vector_type(4))) float floatx4;
typedef __attribute__((ext_vector_type(2))) float float2v;
union Frag { int4 i; short8 s; };

__device__ __forceinline__ float2v fma2(float2v a, float2v b, float2v c){
  return __builtin_elementwise_fma(a, b, c);
}
__device__ __forceinline__ float geluf(float x){
  float u = 1.5957691216057308f * (x + 0.044715f*x*x*x);
  return x * __builtin_amdgcn_rcpf(1.f + __expf(-u));
}
__device__ __forceinline__ float softplus_f(float x){
  return (x > 20.f) ? x : log1pf(__expf(x));
}
__device__ __forceinline__ float logsig_f(float x){
  return -softplus_f(-x);
}
__device__ __forceinline__ unsigned short f2bf(float f){
  unsigned int u = __builtin_bit_cast(unsigned int, f);
  u += 0x7fffu + ((u >> 16) & 1u);
  return (unsigned short)(u >> 16);
}
// HW packed f32->bf16 (RNE, matches f2bf). REGIME NOTE (r7-r10 2x2): this asm
// version profiles SLOWER under rocprof (serialized, cold-cache, latency-bound)
// but runs FASTER on the graded wall clock (warm-cache, VALU-bound: 680/680/676
// vs 742/754). Trust wall A/Bs for VALU-side changes here.
// r12 lesson: 48-col tile (512 blocks @ 2/CU exact) lost 190us to occupancy
// collapse -- keep 768 blocks @ 3/CU (grid slack > halo efficiency).
__device__ __forceinline__ unsigned int packbf2(float a0, float a1){
  unsigned int r;
  asm("v_cvt_pk_bf16_f32 %0, %1, %2" : "=v"(r) : "v"(a0), "v"(a1));
  return r;
}
__device__ __forceinline__ void unbf2(unsigned int u, float& lo, float& hi){
  lo = __builtin_bit_cast(float, u << 16);
  hi = __builtin_bit_cast(float, u & 0xffff0000u);
}
__device__ __forceinline__ float2v unbf2v(unsigned int u){
  float2v r;
  r.x = __builtin_bit_cast(float, u << 16);
  r.y = __builtin_bit_cast(float, u & 0xffff0000u);
  return r;
}
__device__ __forceinline__ void unp8(int4 v, float* o){
  unsigned int* p = (unsigned int*)&v;
  unbf2(p[0], o[0], o[1]); unbf2(p[1], o[2], o[3]);
  unbf2(p[2], o[4], o[5]); unbf2(p[3], o[6], o[7]);
}
__device__ __forceinline__ void f4arr(float4 v, float* o){ o[0]=v.x;o[1]=v.y;o[2]=v.z;o[3]=v.w; }
__device__ __forceinline__ float2v pick2(float4 a, float4 b, int p){
  switch(p){
    case 0: return (float2v){a.x, a.y};
    case 1: return (float2v){a.z, a.w};
    case 2: return (float2v){b.x, b.y};
    default: return (float2v){b.z, b.w};
  }
}

// ---------------- weight f32 -> bf16 swizzled fragment order ----------------
__global__ __launch_bounds__(256) void convert_w_k(
    const float* __restrict__ p0, const float* __restrict__ p1,
    const float* __restrict__ p2, const float* __restrict__ p3,
    const float* __restrict__ p4, const float* __restrict__ p5,
    const float* __restrict__ p6, const float* __restrict__ p7,
    const float* __restrict__ p8, unsigned short* __restrict__ Wb){
  int i = blockIdx.x*256 + threadIdx.x;
  const int totalA = 33*WSLOT;
  const int total = totalA + 8*PSW;
  if (i >= total) return;
  if (i < totalA){
    int slot = i / WSLOT, j = i % WSLOT;
    int e = j & 7, lane = (j>>3) & 63, kt = j >> 9;
    int k = kt % 6, tile = kt / 6;
    int co = tile*16 + (lane & 15);
    int kk = k*32 + (lane>>4)*8 + e;
    int r = co*CC + kk;
    const float* src;
    if      (slot == 0) src = p0 + r;
    else if (slot == 1) src = p1 + r;
    else if (slot == 2) src = p2 + r;
    else if (slot < 6)  src = p3 + (size_t)(slot-3)*WSLOT + r;
    else if (slot < 9)  src = p4 + (size_t)(slot-6)*WSLOT + r;
    else if (slot < 21) src = p5 + (size_t)(slot-9)*WSLOT + r;
    else                src = p6 + (size_t)(slot-21)*WSLOT + r;
    Wb[i] = f2bf(*src);
  } else {
    int r2 = i - totalA;
    int ps = r2 / PSW, j = r2 % PSW;
    int e = j & 7, lane = (j>>3) & 63, kt = j >> 9;
    int k = kt % 6, tile = kt / 6;
    int co = tile*16 + (lane & 15); if (co > PP-1) co = PP-1;
    int kk = k*32 + (lane>>4)*8 + e;
    const float* base = (ps < 4) ? (p7 + (size_t)ps*PP*CC) : (p8 + (size_t)(ps-4)*PP*CC);
    Wb[i] = f2bf(base[co*CC + kk]);
  }
}

// ---------------- per-layer params -> [set][layer][9][192] f32 ----------------
__global__ __launch_bounds__(256) void pack_par_k(
    const float* __restrict__ dds_dep_w, const float* __restrict__ dds_dep_b,
    const float* __restrict__ dds_ln_g,  const float* __restrict__ dds_ln_b,
    const float* __restrict__ dds_pw_b,
    const float* __restrict__ pdds_dep_w, const float* __restrict__ pdds_dep_b,
    const float* __restrict__ pdds_ln_g,  const float* __restrict__ pdds_ln_b,
    const float* __restrict__ pdds_pw_b,
    const float* __restrict__ p_dep_w, const float* __restrict__ p_dep_b,
    const float* __restrict__ p_ln_g,  const float* __restrict__ p_ln_b,
    const float* __restrict__ p_pw_b,
    const float* __restrict__ f_dep_w, const float* __restrict__ f_dep_b,
    const float* __restrict__ f_ln_g,  const float* __restrict__ f_ln_b,
    const float* __restrict__ f_pw_b,
    float* __restrict__ P){
  int i = blockIdx.x*256 + threadIdx.x;
  const int total = 30*PARL;
  if (i >= total) return;
  int ls = i / PARL, r = i % PARL;
  int arr = r / 192, c = r % 192;
  const float *dep_w, *dep_b, *ln_g, *ln_b, *pw_b;
  int l;
  if (ls < 3){
    l = ls; dep_w = dds_dep_w; dep_b = dds_dep_b; ln_g = dds_ln_g; ln_b = dds_ln_b; pw_b = dds_pw_b;
  } else if (ls < 6){
    l = ls-3; dep_w = pdds_dep_w; dep_b = pdds_dep_b; ln_g = pdds_ln_g; ln_b = pdds_ln_b; pw_b = pdds_pw_b;
  } else if (ls < 18){
    int f = (ls-6)/3; l = (ls-6)%3;
    dep_w = p_dep_w + (size_t)f*3*CC*3; dep_b = p_dep_b + (size_t)f*3*CC;
    ln_g = p_ln_g + (size_t)f*3*2*CC;  ln_b = p_ln_b + (size_t)f*3*2*CC;
    pw_b = p_pw_b + (size_t)f*3*CC;
  } else {
    int f = (ls-18)/3; l = (ls-18)%3;
    dep_w = f_dep_w + (size_t)f*3*CC*3; dep_b = f_dep_b + (size_t)f*3*CC;
    ln_g = f_ln_g + (size_t)f*3*2*CC;  ln_b = f_ln_b + (size_t)f*3*2*CC;
    pw_b = f_pw_b + (size_t)f*3*CC;
  }
  float v;
  if      (arr < 3)  v = dep_w[((size_t)l*CC + c)*3 + arr];
  else if (arr == 3) v = dep_b[(size_t)l*CC + c];
  else if (arr == 4) v = ln_g[((size_t)l*2+0)*CC + c];
  else if (arr == 5) v = ln_b[((size_t)l*2+0)*CC + c];
  else if (arr == 6) v = ln_g[((size_t)l*2+1)*CC + c];
  else if (arr == 7) v = ln_b[((size_t)l*2+1)*CC + c];
  else               v = pw_b[(size_t)l*CC + c];
  P[i] = v;
}

// -------- fused: x f32 [B][C][T] -> transpose -> conv1x1(pre) -> A bf16 [B][T][C] ----
__global__ __launch_bounds__(256) void trans_conv_k(
    const float* __restrict__ x, const unsigned short* __restrict__ Wsw,
    const float* __restrict__ bias, unsigned short* __restrict__ outb){
  __shared__ unsigned short bufX[32*XS];
  int b = blockIdx.y, t0 = blockIdx.x*32, tid = threadIdx.x;
  int tl4 = (tid & 7)*4, cr = tid >> 3;
  #pragma unroll
  for (int rnd=0; rnd<6; rnd++){
    int c = rnd*32 + cr;
    float4 v4 = *(const float4*)(x + ((size_t)b*CC + c)*TTT + t0 + tl4);
    bufX[(tl4+0)*XS + c] = f2bf(v4.x);
    bufX[(tl4+1)*XS + c] = f2bf(v4.y);
    bufX[(tl4+2)*XS + c] = f2bf(v4.z);
    bufX[(tl4+3)*XS + c] = f2bf(v4.w);
  }
  __syncthreads();
  int w = tid >> 6, lane = tid & 63;
  int n16 = lane & 15, quad = lane >> 4;
  Frag af[3][6];
  #pragma unroll
  for (int ct=0; ct<3; ct++){
    int tile = w*3 + ct;
    #pragma unroll
    for (int k=0;k<6;k++)
      af[ct][k].i = *(const int4*)(Wsw + ((size_t)(tile*6 + k)*64 + lane)*8);
  }
  floatx4 acc[3][2];
  #pragma unroll
  for (int ct=0;ct<3;ct++)
    #pragma unroll
    for (int tt=0;tt<2;tt++)
      acc[ct][tt] = (floatx4){0.f,0.f,0.f,0.f};
  #pragma unroll
  for (int k=0;k<6;k++){
    Frag bf[2];
    #pragma unroll
    for (int tt=0;tt<2;tt++)
      bf[tt].i = *(const int4*)&bufX[(tt*16+n16)*XS + k*32 + quad*8];
    #pragma unroll
    for (int ct=0;ct<3;ct++)
      #pragma unroll
      for (int tt=0;tt<2;tt++)
        acc[ct][tt] = __builtin_amdgcn_mfma_f32_16x16x32_bf16(af[ct][k].s, bf[tt].s, acc[ct][tt], 0,0,0);
  }
  __syncthreads();
  #pragma unroll
  for (int ct=0;ct<3;ct++){
    int cobase = w*48 + ct*16 + quad*4;
    float4 b4 = *(const float4*)(bias + cobase);
    #pragma unroll
    for (int tt=0;tt<2;tt++){
      int t = tt*16 + n16;
      uint2 wv;
      wv.x = packbf2(acc[ct][tt][0] + b4.x, acc[ct][tt][1] + b4.y);
      wv.y = packbf2(acc[ct][tt][2] + b4.z, acc[ct][tt][3] + b4.w);
      *(uint2*)&bufX[t*XS + cobase] = wv;
    }
  }
  __syncthreads();
  #pragma unroll
  for (int k=0;k<3;k++){
    int task = k*256 + tid;
    int row = task/24, cn = task%24;
    *(int4*)(outb + ((size_t)b*TTT + t0 + row)*CC + cn*8) = *(const int4*)&bufX[row*XS + cn*8];
  }
}

// ---------------- one fused DDS layer, compile-time peeled ----------------
// DIL: dilation (1,3,9). SPLITF=0: all 4 waves own 16 rows each, 12 co-tiles.
// SPLITF=1 (layer 2): wave-pair (w>>1) owns 16 rows, half (w&1) owns 6 co-tiles.
// Rules (r1-r3 lessons): static register-array indices only; no pre-barrier
// prefetch with cross-barrier register liveness (scratch demotion).
// P4: depth-1 double-buffer (load NEXT tile into the OTHER buffer).
template<int DIL, int SPLITF>
__device__ __forceinline__ void dds_layer(
    unsigned short* __restrict__ ping,
    const float* __restrict__ pl,
    float* __restrict__ pnd, const float* __restrict__ pns,
    const float* __restrict__ mrow,
    float (* __restrict__ sqx)[2][2],
    const unsigned short* __restrict__ WL,
    int tid, int w, int lane, int n16, int quad, int row){
  constexpr int NT = SPLITF ? 6 : 12;
  const int tb = SPLITF ? ((w & 1)*6) : 0;
  const int rowL = SPLITF ? (16 + (w>>1)*16 + n16) : row;
  Frag bfr[6];
  floatx4 acc[NT];
  {
    int iL = rowL - DIL; iL = iL < 0 ? 0 : iL;
    int iR = rowL + DIL; iR = iR > 63 ? 63 : iR;
    float2v vv[24];
    float2v s2v = {0.f,0.f}, q2v = {0.f,0.f};
    #pragma unroll
    for (int j=0;j<6;j++){
      int kk = j*32 + quad*8;
      int4 L4 = *(const int4*)&ping[iL*XSP + kk];
      int4 C4 = *(const int4*)&ping[rowL*XSP + kk];
      int4 R4 = *(const int4*)&ping[iR*XSP + kk];
      unsigned int* Lp = (unsigned int*)&L4;
      unsigned int* Cp = (unsigned int*)&C4;
      unsigned int* Rp = (unsigned int*)&R4;
      float4 w0a = *(const float4*)&pl[kk],       w0b = *(const float4*)&pl[kk+4];
      float4 w1a = *(const float4*)&pl[192+kk],   w1b = *(const float4*)&pl[192+kk+4];
      float4 w2a = *(const float4*)&pl[384+kk],   w2b = *(const float4*)&pl[384+kk+4];
      float4 dba = *(const float4*)&pl[576+kk],   dbb = *(const float4*)&pl[576+kk+4];
      #pragma unroll
      for (int p=0;p<4;p++){
        float2v val = fma2(pick2(w0a,w0b,p), unbf2v(Lp[p]),
                      fma2(pick2(w1a,w1b,p), unbf2v(Cp[p]),
                      fma2(pick2(w2a,w2b,p), unbf2v(Rp[p]), pick2(dba,dbb,p))));
        vv[j*4+p] = val;
        s2v += val;
        q2v = fma2(val, val, q2v);
      }
    }
    float s = s2v.x + s2v.y, q = q2v.x + q2v.y;
    s += __shfl_xor(s, 16); s += __shfl_xor(s, 32);
    q += __shfl_xor(q, 16); q += __shfl_xor(q, 32);
    float mm = s*(1.f/CC);
    float rr = rsqrtf(q*(1.f/CC) - mm*mm + 1e-5f);
    // P3: LN + gelu -> B fragments in registers
    float2v mm2 = {mm,mm}, rr2 = {rr,rr};
    #pragma unroll
    for (int j=0;j<6;j++){
      int kk = j*32 + quad*8;
      float4 g0a = *(const float4*)&pl[768+kk], g0b = *(const float4*)&pl[768+kk+4];
      float4 b0a = *(const float4*)&pl[960+kk], b0b = *(const float4*)&pl[960+kk+4];
      unsigned int wwp[4];
      #pragma unroll
      for (int p=0;p<4;p++){
        float2v a = fma2((vv[j*4+p]-mm2)*rr2, pick2(g0a,g0b,p), pick2(b0a,b0b,p));
        wwp[p] = packbf2(geluf(a.x), geluf(a.y));
      }
      bfr[j].i = make_int4((int)wwp[0], (int)wwp[1], (int)wwp[2], (int)wwp[3]);
    }
  }
  __syncthreads();   // all P1 ping reads done before in-place P6 writes
  // stage next layer's params (overlaps P4; visible at end-of-layer barrier)
  if (pns){
    #pragma unroll
    for (int k=0;k<7;k++){
      int i2 = k*256 + tid;
      if (i2 < PARL) pnd[i2] = pns[i2];
    }
  }
  // P4: stream NT A-tiles with depth-1 software double-buffer, B from registers
  {
    Frag afb[2][6];
    #pragma unroll
    for (int k=0;k<6;k++)
      afb[0][k].i = *(const int4*)(WL + ((size_t)((tb+0)*6 + k)*64 + lane)*8);
    #pragma unroll
    for (int tile=0; tile<NT; tile++){
      int cur = tile & 1, nxt = cur ^ 1;
      if (tile < NT-1){
        #pragma unroll
        for (int k=0;k<6;k++)
          afb[nxt][k].i = *(const int4*)(WL + ((size_t)((tb+tile+1)*6 + k)*64 + lane)*8);
      }
      acc[tile] = (floatx4){0.f,0.f,0.f,0.f};
      #pragma unroll
      for (int k=0;k<6;k++)
        acc[tile] = __builtin_amdgcn_mfma_f32_16x16x32_bf16(afb[cur][k].s, bfr[k].s, acc[tile], 0,0,0);
    }
  }
  // bias + conv-LN stats (packed, in-wave)
  float2v s2p = {0.f,0.f}, q2p = {0.f,0.f};
  #pragma unroll
  for (int tile=0; tile<NT; tile++){
    int co = (tb+tile)*16 + quad*4;
    float4 pbv = *(const float4*)&pl[1536+co];
    acc[tile][0] += pbv.x; acc[tile][1] += pbv.y;
    acc[tile][2] += pbv.z; acc[tile][3] += pbv.w;
    float2v v01 = {acc[tile][0], acc[tile][1]};
    float2v v23 = {acc[tile][2], acc[tile][3]};
    s2p += v01 + v23;
    q2p = fma2(v01, v01, q2p);
    q2p = fma2(v23, v23, q2p);
  }
  float s2 = s2p.x + s2p.y, q2 = q2p.x + q2p.y;
  s2 += __shfl_xor(s2, 16); s2 += __shfl_xor(s2, 32);
  q2 += __shfl_xor(q2, 16); q2 += __shfl_xor(q2, 32);
  if constexpr (SPLITF){
    int r16 = rowL - 16;
    if (quad == 0){ sqx[r16][w&1][0] = s2; sqx[r16][w&1][1] = q2; }
    __syncthreads();
    int oh = (w&1)^1;
    s2 += sqx[r16][oh][0];
    q2 += sqx[r16][oh][1];
  }
  float cmP = s2*(1.f/CC);
  float crP = rsqrtf(q2*(1.f/CC) - cmP*cmP + 1e-5f);
  // P6: LN + gelu + residual, apply row mask, in-place
  float mc = mrow[rowL];
  float2v mc2 = {mc,mc};
  float2v cm2 = {cmP,cmP}, cr2 = {crP,crP};
  #pragma unroll
  for (int tile=0; tile<NT; tile++){
    int co = (tb+tile)*16 + quad*4;
    float4 g1v = *(const float4*)&pl[1152+co];
    float4 b1v = *(const float4*)&pl[1344+co];
    uint2 ux = *(uint2*)&ping[rowL*XSP + co];
    float2v x01 = unbf2v(ux.x), x23 = unbf2v(ux.y);
    float2v v01 = {acc[tile][0], acc[tile][1]};
    float2v v23 = {acc[tile][2], acc[tile][3]};
    float2v a01 = fma2((v01-cm2)*cr2, (float2v){g1v.x,g1v.y}, (float2v){b1v.x,b1v.y});
    float2v a23 = fma2((v23-cm2)*cr2, (float2v){g1v.z,g1v.w}, (float2v){b1v.z,b1v.w});
    float2v h01 = (x01 + (float2v){geluf(a01.x), geluf(a01.y)}) * mc2;
    float2v h23 = (x23 + (float2v){geluf(a23.x), geluf(a23.y)}) * mc2;
    uint2 wv;
    wv.x = packbf2(h01.x, h01.y);
    wv.y = packbf2(h23.x, h23.y);
    *(uint2*)&ping[rowL*XSP + co] = wv;
  }
  __syncthreads();   // P6 writes + par staging visible
}

// ---------------- mega DDS v16 == v14 (r11 restore): 32-col tile, 4 waves --------
// outmode=1: flow path (proj 29x192 + RQS). outmode=2: conv tail (r7).
// pmode: 0 none; 1 init fused (p0); 2 transition-stage (f0); 3 transition-rqs (f1).
// finmode=1 (f3): adds 0.5(log2pi+z^2) of both final channels in RQS.
// Race audit: intra-dispatch cross-block z traffic is only (a) halo READS of the
// staged channel and (b) benign pass-through writes old*m (mask binary) -> safe.
__global__ __launch_bounds__(256,3) void mega_dds_k(
    const unsigned short* __restrict__ in,
    const float* __restrict__ zsrc, int zstride,
    const unsigned short* __restrict__ g,
    const float* __restrict__ mask,
    const float* __restrict__ parP,     // 3 layers x PARL floats
    const float* __restrict__ pw1, const float* __restrict__ pb1,
    const unsigned short* __restrict__ Wsw,
    int srcmode, int outmode,
    const unsigned short* __restrict__ projW, const float* __restrict__ projB,
    float* __restrict__ z, int zs, float* __restrict__ acco,
    const unsigned short* __restrict__ cvW, const float* __restrict__ cvB,
    const unsigned short* __restrict__ addsrc, unsigned short* __restrict__ cvout,
    int cvmode,
    int pmode, int finmode, const float* __restrict__ aux,
    const float* __restrict__ pmv, const float* __restrict__ plv){
  __shared__ unsigned short ping[64*XSP];   // bf16 [window row][c], masked residual stream
  __shared__ float par[2][PARL];            // per-layer params, double-buffered
  __shared__ float mrow[64];
  __shared__ float sqx[32][2][2];           // layer-2 LN stat exchange [row16][half][s,q]
  float* pro = par[0];                      // alias: used only after all layers done

  int b = blockIdx.y, t0 = blockIdx.x*32, tid = threadIdx.x;
  int ws0 = t0 - 16;
  int w = tid >> 6, lane = tid & 63;
  int n16 = lane & 15, quad = lane >> 4;
  int row = w*16 + n16;                      // this lane's window row (layers 0,1)
  const float* mkb = mask + (size_t)b*TTT;

  // uniform per-mode scalars (affine constants)
  float pm0=0.f, pm1=0.f, lg0=0.f, lg1=0.f, ex0=0.f, ex1=0.f;
  if (pmode){
    pm0 = pmv[0]; pm1 = pmv[1]; lg0 = plv[0]; lg1 = plv[1];
    ex0 = __expf(lg0); ex1 = __expf(lg1);
  }

  if (tid < 64){
    int gt = ws0 + tid;
    bool inr = (gt >= 0) && (gt < TTT);
    int gc = gt < 0 ? 0 : (gt > TTT-1 ? TTT-1 : gt);
    mrow[tid] = inr ? mkb[gc] : 0.f;
  }
  // stage layer-0 params
  #pragma unroll
  for (int k=0;k<7;k++){
    int i2 = k*256 + tid;
    if (i2 < PARL) par[0][i2] = parP[i2];
  }
  // ---- staging (pre-masked) ----
  if (srcmode == 0){
    #pragma unroll
    for (int k=0;k<6;k++){
      int task = k*256 + tid;
      int r = task/24, cn = task%24, c0 = cn*8;
      int gt = ws0 + r;
      bool inr = (gt >= 0) && (gt < TTT);
      int gc = gt < 0 ? 0 : (gt > TTT-1 ? TTT-1 : gt);
      float mv = inr ? mkb[gc] : 0.f;
      float hv[8];
      unp8(*(const int4*)(in + ((size_t)b*TTT + gc)*CC + c0), hv);
      int4 pk;
      pk.x = (int)packbf2(hv[0]*mv, hv[1]*mv); pk.y = (int)packbf2(hv[2]*mv, hv[3]*mv);
      pk.z = (int)packbf2(hv[4]*mv, hv[5]*mv); pk.w = (int)packbf2(hv[6]*mv, hv[7]*mv);
      *(int4*)&ping[r*XSP + c0] = pk;
    }
  } else {
    #pragma unroll
    for (int k=0;k<6;k++){
      int task = k*256 + tid;
      int r = task/24, cn = task%24, c0 = cn*8;
      int gt = ws0 + r;
      bool inr = (gt >= 0) && (gt < TTT);
      int gc = gt < 0 ? 0 : (gt > TTT-1 ? TTT-1 : gt);
      float mv = inr ? mkb[gc] : 0.f;
      float zv;
      if (pmode == 1){
        float e0 = aux[((size_t)b*2+0)*TTT + gc] * mv;
        zv = fmaf(ex0, e0, pm0)*mv;
      } else if (pmode == 2){
        float zu = zsrc[(size_t)b*zstride + gc];
        float wv = aux[(size_t)b*TTT + gc];
        float u  = mv / (1.f + __expf(-zu));
        float y0 = logf(fmaxf((wv - u)*mv, 1e-5f))*mv;
        zv = fmaf(ex0, y0, pm0)*mv;
      } else {
        zv = inr ? zsrc[(size_t)b*zstride + gc] : 0.f;
      }
      float hv[8];
      if (g){
        unp8(*(const int4*)(g + ((size_t)b*TTT + gc)*CC + c0), hv);
      } else {
        #pragma unroll
        for (int e=0;e<8;e++) hv[e] = 0.f;
      }
      float4 pwa = *(const float4*)(pw1 + c0);
      float4 pwb2 = *(const float4*)(pw1 + c0 + 4);
      float4 pba = *(const float4*)(pb1 + c0);
      float4 pbb2 = *(const float4*)(pb1 + c0 + 4);
      float pwv[8], pbv[8];
      f4arr(pwa, pwv); f4arr(pwb2, pwv+4);
      f4arr(pba, pbv); f4arr(pbb2, pbv+4);
      float ov[8];
      #pragma unroll
      for (int e=0;e<8;e++) ov[e] = (hv[e] + fmaf(pwv[e], zv, pbv[e]))*mv;
      int4 pk;
      pk.x = (int)packbf2(ov[0], ov[1]); pk.y = (int)packbf2(ov[2], ov[3]);
      pk.z = (int)packbf2(ov[4], ov[5]); pk.w = (int)packbf2(ov[6], ov[7]);
      *(int4*)&ping[r*XSP + c0] = pk;
    }
  }
  __syncthreads();

  // ---- 3 fused layers, peeled with compile-time shapes ----
  dds_layer<1,0>(ping, par[0], par[1], parP + (size_t)1*PARL, mrow, sqx,
                 Wsw + 0*(size_t)WSLOT, tid, w, lane, n16, quad, row);
  dds_layer<3,0>(ping, par[1], par[0], parP + (size_t)2*PARL, mrow, sqx,
                 Wsw + 1*(size_t)WSLOT, tid, w, lane, n16, quad, row);
  dds_layer<9,1>(ping, par[0], nullptr, nullptr, mrow, sqx,
                 Wsw + 2*(size_t)WSLOT, tid, w, lane, n16, quad, row);

  if (outmode == 2){
    // ---- fused 192x192 conv tail on center rows (r7, unchanged) ----
    if (cvmode == 2){
      #pragma unroll
      for (int k=0;k<3;k++){
        int task = k*256 + tid;
        int r = task/24, cn = task%24;
        int dr = r + ((r >= 16) ? 32 : 0);
        *(int4*)&ping[dr*XSP + cn*8] =
            *(const int4*)(addsrc + ((size_t)b*TTT + t0 + r)*CC + cn*8);
      }
    }
    Frag af[3][6];
    #pragma unroll
    for (int ct=0; ct<3; ct++){
      int tile = w*3 + ct;
      #pragma unroll
      for (int k=0;k<6;k++)
        af[ct][k].i = *(const int4*)(cvW + ((size_t)(tile*6 + k)*64 + lane)*8);
    }
    floatx4 acc2[3][2];
    #pragma unroll
    for (int ct=0;ct<3;ct++)
      #pragma unroll
      for (int tt=0;tt<2;tt++)
        acc2[ct][tt] = (floatx4){0.f,0.f,0.f,0.f};
    #pragma unroll
    for (int k=0;k<6;k++){
      Frag bf[2];
      #pragma unroll
      for (int tt=0;tt<2;tt++)
        bf[tt].i = *(const int4*)&ping[(16 + tt*16 + n16)*XSP + k*32 + quad*8];
      #pragma unroll
      for (int ct=0;ct<3;ct++)
        #pragma unroll
        for (int tt=0;tt<2;tt++)
          acc2[ct][tt] = __builtin_amdgcn_mfma_f32_16x16x32_bf16(af[ct][k].s, bf[tt].s, acc2[ct][tt], 0,0,0);
    }
    __syncthreads();   // center reads + halo staging complete
    #pragma unroll
    for (int ct=0;ct<3;ct++){
      int cobase = w*48 + ct*16 + quad*4;
      float4 b4 = *(const float4*)(cvB + cobase);
      float ba[4] = {b4.x, b4.y, b4.z, b4.w};
      #pragma unroll
      for (int tt=0;tt<2;tt++){
        int t = tt*16 + n16;
        float mv = mrow[16 + t];
        float av[4] = {0.f,0.f,0.f,0.f};
        if (cvmode == 2){
          int hr = t + ((t >= 16) ? 32 : 0);
          uint2 uy = *(uint2*)&ping[hr*XSP + cobase];
          unbf2(uy.x, av[0], av[1]); unbf2(uy.y, av[2], av[3]);
        }
        float hh[4];
        #pragma unroll
        for (int r=0;r<4;r++){
          float v = (acc2[ct][tt][r] + ba[r]) * mv;
          if (cvmode == 2) v += av[r];
          hh[r] = v;
        }
        uint2 wv; wv.x = packbf2(hh[0], hh[1]); wv.y = packbf2(hh[2], hh[3]);
        *(uint2*)&ping[(16 + t)*XSP + cobase] = wv;
      }
    }
    __syncthreads();
    #pragma unroll
    for (int k=0;k<3;k++){
      int task = k*256 + tid;
      int r = task/24, cn = task%24, c0 = cn*8;
      *(int4*)(cvout + ((size_t)b*TTT + t0 + r)*CC + c0) = *(const int4*)&ping[(16+r)*XSP + c0];
    }
    return;
  }

  // ---- proj (29x192) on center rows: all 4 waves, each one (rowgroup, ct) ----
  {
    int ctp = w & 1;
    int prow = 16 + (w>>1)*16 + n16;        // 16..47
    Frag afp[6];
    #pragma unroll
    for (int k=0;k<6;k++)
      afp[k].i = *(const int4*)(projW + ((size_t)(ctp*6 + k)*64 + lane)*8);
    Frag bfp[6];
    #pragma unroll
    for (int k=0;k<6;k++)
      bfp[k].i = *(const int4*)&ping[prow*XSP + k*32 + quad*8];
    floatx4 acc2 = (floatx4){0.f,0.f,0.f,0.f};
    #pragma unroll
    for (int k=0;k<6;k++)
      acc2 = __builtin_amdgcn_mfma_f32_16x16x32_bf16(afp[k].s, bfp[k].s, acc2, 0,0,0);
    int rt = prow - 16;                     // 0..31
    float mv = mrow[prow];
    #pragma unroll
    for (int r=0;r<4;r++){
      int co = ctp*16 + quad*4 + r;
      if (co < PP) pro[rt*30 + co] = (acc2[r] + projB[co]) * mv;
    }
  }
  __syncthreads();
  // ---- RQS spline on 32 lanes (+ fused init/transition/final terms) ----
  if (tid < 32){
    const float scv = 0.07216878364870323f;   // 1/sqrt(192)
    int tg = t0 + tid;
    float m = mrow[16+tid];
    float* z0p = z + ((size_t)b*2 + zs)*TTT + tg;
    float* z1p = z + ((size_t)b*2 + (1-zs))*TTT + tg;
    float xs, zwr0, extra = 0.f;
    if (pmode == 1){
      float e0c = aux[((size_t)b*2+0)*TTT + tg]*m;
      float e1c = aux[((size_t)b*2+1)*TTT + tg]*m;
      zwr0 = fmaf(ex0, e0c, pm0)*m;
      xs   = fmaf(ex1, e1c, pm1)*m;
      extra = -0.5f*(LOG2PI_F + e0c*e0c)*m - 0.5f*(LOG2PI_F + e1c*e1c)*m - (lg0+lg1)*m;
    } else if (pmode == 2){
      xs = fmaf(ex1, *z1p, pm1)*m;
      zwr0 = (*z0p)*m;
    } else if (pmode == 3){
      float zu = *z1p;                    // ch pre-transition (center-local)
      float wv = aux[(size_t)b*TTT + tg];
      float u  = m/(1.f + __expf(-zu));
      float y0 = logf(fmaxf((wv - u)*m, 1e-5f))*m;
      xs = fmaf(ex0, y0, pm0)*m;
      extra = -(logsig_f(zu)+logsig_f(-zu))*m + y0 - (lg0+lg1)*m;
      zwr0 = (*z0p)*m;
    } else {
      xs = *z1p;
      zwr0 = (*z0p)*m;
    }
    float uw[10], uh[10], ud[9];
    #pragma unroll
    for (int k=0;k<10;k++) uw[k]=pro[tid*30+k]*scv;
    #pragma unroll
    for (int k=0;k<10;k++) uh[k]=pro[tid*30+10+k]*scv;
    #pragma unroll
    for (int k=0;k<9;k++)  ud[k]=pro[tid*30+20+k];
    bool inside = (xs >= -5.f) && (xs <= 5.f);
    float xc = fminf(fmaxf(xs,-5.f),5.f);
    float mx=uw[0];
    #pragma unroll
    for (int k=1;k<10;k++) mx=fmaxf(mx,uw[k]);
    float sw=0.f; float wd[10];
    #pragma unroll
    for (int k=0;k<10;k++){ wd[k]=__expf(uw[k]-mx); sw+=wd[k]; }
    float invw = 1.f/sw;
    #pragma unroll
    for (int k=0;k<10;k++) wd[k]=fmaf(0.99f*invw, wd[k], 1e-3f);
    float mh=uh[0];
    #pragma unroll
    for (int k=1;k<10;k++) mh=fmaxf(mh,uh[k]);
    float sh=0.f; float ht[10];
    #pragma unroll
    for (int k=0;k<10;k++){ ht[k]=__expf(uh[k]-mh); sh+=ht[k]; }
    float invh = 1.f/sh;
    #pragma unroll
    for (int k=0;k<10;k++) ht[k]=fmaf(0.99f*invh, ht[k], 1e-3f);
    float cw=-5.f, icw=-5.f, iw=1.f; int idx=0;
    #pragma unroll
    for (int i2=0;i2<10;i2++){
      float nw = (i2==9) ? 5.f : fmaf(10.f, wd[i2], cw);
      if (cw <= xc){ idx=i2; icw=cw; iw=nw-cw; }
      cw=nw;
    }
    float ch=-5.f, ich=-5.f, ih=1.f;
    #pragma unroll
    for (int i2=0;i2<10;i2++){
      float nh = (i2==9) ? 5.f : fmaf(10.f, ht[i2], ch);
      if (i2==idx){ ich=ch; ih=nh-ch; }
      ch=nh;
    }
    const float UDC = logf(expm1f(0.999f));
    float d0=1.f, d1=1.f;
    #pragma unroll
    for (int k=0;k<11;k++){
      float uu = (k==0 || k==10) ? UDC : ud[k-1];
      float dk = 1e-3f + softplus_f(uu);
      if (k==idx)   d0=dk;
      if (k==idx+1) d1=dk;
    }
    float idel = ih/iw;
    float th = (xc-icw)/iw;
    float t1m = th*(1.f-th);
    float den = idel + (d0+d1-2.f*idel)*t1m;
    float outv = ich + ih*(idel*th*th + d0*t1m)/den;
    float omt = 1.f-th;
    float dnum = idel*idel*(d1*th*th + 2.f*idel*t1m + d0*omt*omt);
    float lad = logf(dnum) - 2.f*logf(den);
    float y = inside ? outv : xs;
    lad = inside ? lad : 0.f;
    float y1 = y*m;
    *z1p = y1;
    *z0p = zwr0;
    if (finmode){
      extra += 0.5f*(LOG2PI_F + y1*y1)*m + 0.5f*(LOG2PI_F + zwr0*zwr0)*m;
    }
    float c = extra - lad*m;
    c += __shfl_xor(c, 1); c += __shfl_xor(c, 2);
    c += __shfl_xor(c, 4); c += __shfl_xor(c, 8);
    c += __shfl_xor(c, 16);
    if (tid == 0) atomicAdd(acco + b, c);
  }
}

__global__ void write_out_k(const float* __restrict__ acc, float* __restrict__ out, int n){
  int i = threadIdx.x;
  if (i < n) out[i] = acc[i];
}

extern "C" void kernel_launch(void* const* d_in, const int* in_sizes, int n_in,
                              void* d_out, int out_size, void* d_ws, size_t ws_size,
                              hipStream_t stream){
  (void)n_in; (void)out_size; (void)ws_size;
  const float* x         = (const float*)d_in[0];
  const float* mask      = (const float*)d_in[1];
  const float* w_in      = (const float*)d_in[2];
  const float* e_q       = (const float*)d_in[3];
  const float* pre_w     = (const float*)d_in[4];
  const float* pre_b     = (const float*)d_in[5];
  const float* proj_w    = (const float*)d_in[6];
  const float* proj_b    = (const float*)d_in[7];
  const float* dds_dep_w = (const float*)d_in[8];
  const float* dds_dep_b = (const float*)d_in[9];
  const float* dds_pw_w  = (const float*)d_in[10];
  const float* dds_pw_b  = (const float*)d_in[11];
  const float* dds_ln_g  = (const float*)d_in[12];
  const float* dds_ln_b  = (const float*)d_in[13];
  const float* post_pre_w  = (const float*)d_in[14];
  const float* post_pre_b  = (const float*)d_in[15];
  const float* post_proj_w = (const float*)d_in[16];
  const float* post_proj_b = (const float*)d_in[17];
  const float* pdds_dep_w  = (const float*)d_in[18];
  const float* pdds_dep_b  = (const float*)d_in[19];
  const float* pdds_pw_w   = (const float*)d_in[20];
  const float* pdds_pw_b   = (const float*)d_in[21];
  const float* pdds_ln_g   = (const float*)d_in[22];
  const float* pdds_ln_b   = (const float*)d_in[23];
  const float* aff_m    = (const float*)d_in[24];
  const float* aff_logs = (const float*)d_in[25];
  const float* f_pre_w  = (const float*)d_in[26];
  const float* f_pre_b  = (const float*)d_in[27];
  const float* f_dep_w  = (const float*)d_in[28];
  const float* f_dep_b  = (const float*)d_in[29];
  const float* f_pw_w   = (const float*)d_in[30];
  const float* f_pw_b   = (const float*)d_in[31];
  const float* f_ln_g   = (const float*)d_in[32];
  const float* f_ln_b   = (const float*)d_in[33];
  const float* f_proj_w = (const float*)d_in[34];
  const float* f_proj_b = (const float*)d_in[35];
  const float* paff_m    = (const float*)d_in[36];
  const float* paff_logs = (const float*)d_in[37];
  const float* p_pre_w  = (const float*)d_in[38];
  const float* p_pre_b  = (const float*)d_in[39];
  const float* p_dep_w  = (const float*)d_in[40];
  const float* p_dep_b  = (const float*)d_in[41];
  const float* p_pw_w   = (const float*)d_in[42];
  const float* p_pw_b   = (const float*)d_in[43];
  const float* p_ln_g   = (const float*)d_in[44];
  const float* p_ln_b   = (const float*)d_in[45];
  const float* p_proj_w = (const float*)d_in[46];
  const float* p_proj_b = (const float*)d_in[47];

  int Bn = in_sizes[0] / (CC*TTT);
  size_t big2 = (size_t)Bn*CC*TTT;
  unsigned short* xT = (unsigned short*)d_ws;   // slot kept for layout stability (unused)
  unsigned short* A  = xT + big2;
  unsigned short* Bb = A  + big2;               // unused
  unsigned short* H  = Bb + big2;
  unsigned short* GP = H  + big2;
  unsigned short* Wb = GP + big2;
  size_t wtot = 33*(size_t)WSLOT + 8*(size_t)PSW;
  float* parP = (float*)(Wb + ((wtot + 7) & ~(size_t)7));
  float* zbuf = parP + 30*(size_t)PARL;
  float* acc  = zbuf + (size_t)Bn*2*TTT;

  hipMemsetAsync(acc, 0, Bn*sizeof(float), stream);
  convert_w_k<<<(int)((wtot + 255)/256), 256, 0, stream>>>(
      pre_w, proj_w, post_proj_w, dds_pw_w, pdds_pw_w, p_pw_w, f_pw_w,
      p_proj_w, f_proj_w, Wb);
  pack_par_k<<<(30*PARL + 255)/256, 256, 0, stream>>>(
      dds_dep_w, dds_dep_b, dds_ln_g, dds_ln_b, dds_pw_b,
      pdds_dep_w, pdds_dep_b, pdds_ln_g, pdds_ln_b, pdds_pw_b,
      p_dep_w, p_dep_b, p_ln_g, p_ln_b, p_pw_b,
      f_dep_w, f_dep_b, f_ln_g, f_ln_b, f_pw_b, parP);

  dim3 g32(TTT/32, Bn);
  dim3 b256(256);

  unsigned short* W_pre      = Wb + 0*(size_t)WSLOT;
  unsigned short* W_proj     = Wb + 1*(size_t)WSLOT;
  unsigned short* W_postproj = Wb + 2*(size_t)WSLOT;
  unsigned short* W_dds      = Wb + 3*(size_t)WSLOT;
  unsigned short* W_pdds     = Wb + 6*(size_t)WSLOT;
  unsigned short* W_ppw      = Wb + 9*(size_t)WSLOT;
  unsigned short* W_fpw      = Wb + 21*(size_t)WSLOT;
  unsigned short* W_pproj    = Wb + 33*(size_t)WSLOT;
  unsigned short* W_fproj    = W_pproj + 4*(size_t)PSW;

  // ---- h path: [transpose + conv1x1(pre)] -> mega(+proj tail) -> H ----
  trans_conv_k<<<g32, b256, 0, stream>>>(x, W_pre, pre_b, A);
  mega_dds_k<<<g32, b256, 0, stream>>>(A, nullptr, 0, nullptr, mask,
      parP + 0*(size_t)3*PARL, nullptr, nullptr,
      W_dds, 0, 2, nullptr, nullptr, nullptr, 0, acc,
      W_proj, proj_b, nullptr, H, 1,
      0, 0, nullptr, nullptr, nullptr);

  // ---- hw path: mega(+postproj+H tail) -> GP ----
  mega_dds_k<<<g32, b256, 0, stream>>>(nullptr, w_in, TTT, nullptr, mask,
      parP + 1*(size_t)3*PARL, post_pre_w, post_pre_b,
      W_pdds, 1, 2, nullptr, nullptr, nullptr, 0, acc,
      W_postproj, post_proj_b, H, GP, 2,
      0, 0, nullptr, nullptr, nullptr);

  // ---- 4 posterior flows (g = GP, sets 2..5); flow 0 fuses z-init ----
  for (int f=0; f<4; f++){
    int s = f & 1;
    mega_dds_k<<<g32, b256, 0, stream>>>(nullptr, zbuf + (size_t)s*TTT, 2*TTT, GP, mask,
        parP + (size_t)(2+f)*3*PARL,
        p_pre_w + (size_t)f*CC, p_pre_b + (size_t)f*CC,
        W_ppw + (size_t)f*3*WSLOT, 1, 1,
        W_pproj + (size_t)f*PSW, p_proj_b + (size_t)f*PP, zbuf, s, acc,
        nullptr, nullptr, nullptr, nullptr, 0,
        (f==0) ? 1 : 0, 0, e_q, paff_m, paff_logs);
  }

  // ---- 4 flows (g = H, sets 6..9); flow 0/1 fuse transition, flow 3 fuses final ----
  for (int f=0; f<4; f++){
    int s = f & 1;
    int pmode = (f==0) ? 2 : ((f==1) ? 3 : 0);
    mega_dds_k<<<g32, b256, 0, stream>>>(nullptr, zbuf + (size_t)s*TTT, 2*TTT, H, mask,
        parP + (size_t)(6+f)*3*PARL,
        f_pre_w + (size_t)f*CC, f_pre_b + (size_t)f*CC,
        W_fpw + (size_t)f*3*WSLOT, 1, 1,
        W_fproj + (size_t)f*PSW, f_proj_b + (size_t)f*PP, zbuf, s, acc,
        nullptr, nullptr, nullptr, nullptr, 0,
        pmode, (f==3) ? 1 : 0, w_in, aff_m, aff_logs);
  }

  write_out_k<<<1, 64, 0, stream>>>(acc, (float*)d_out, Bn);
}